// Round 1
// baseline (2168.728 us; speedup 1.0000x reference)
//
#include <hip/hip_runtime.h>
#include <math.h>

static constexpr int CH_IN  = 128;
static constexpr int CH_HID = 128;
static constexpr int CH_OUT = 64;

// ---------- degree / norm precompute ----------

__global__ void k_fill1(float* __restrict__ p, int n) {
    int i = blockIdx.x * blockDim.x + threadIdx.x;
    if (i < n) p[i] = 1.0f;   // self-loop weight
}

__global__ void k_deg(const int* __restrict__ ei, const float* __restrict__ w,
                      float* __restrict__ deg, int E) {
    int e = blockIdx.x * blockDim.x + threadIdx.x;
    if (e < E) unsafeAtomicAdd(&deg[ei[E + e]], w[e]);   // dst-indexed weighted in-degree
}

__global__ void k_dinv(float* __restrict__ deg, int n) {
    int i = blockIdx.x * blockDim.x + threadIdx.x;
    if (i < n) {
        float d = deg[i];
        deg[i] = d > 0.f ? rsqrtf(d) : 0.f;   // in-place: deg -> dinv
    }
}

__global__ void k_norm(const int* __restrict__ ei, const float* __restrict__ w,
                       const float* __restrict__ dinv, float* __restrict__ norm, int E) {
    int e = blockIdx.x * blockDim.x + threadIdx.x;
    if (e < E) norm[e] = dinv[ei[e]] * w[e] * dinv[ei[E + e]];
}

// ---------- fp32 GEMM, register-tiled over rows ----------
// X:[N,128] @ W:[128,COLS] -> H:[N,COLS]; block = COLS threads, ROWS rows/block.
// Each W element loaded once per block feeds ROWS FMAs; x rows staged in LDS
// (broadcast reads, conflict-free).

template<int COLS, int ROWS, bool RELU_IN>
__global__ void k_gemm(const float* __restrict__ X, const float* __restrict__ W,
                       float* __restrict__ H, int N) {
    __shared__ float xs[ROWS][CH_IN];
    const int c = threadIdx.x;
    const int row0 = blockIdx.x * ROWS;
    for (int r = 0; r < ROWS; ++r) {
        int row = row0 + r;
        if (row < N) {
            for (int i = c; i < CH_IN; i += COLS) {
                float v = X[(size_t)row * CH_IN + i];
                if (RELU_IN) v = fmaxf(v, 0.f);
                xs[r][i] = v;
            }
        }
    }
    __syncthreads();
    float acc[ROWS];
    #pragma unroll
    for (int r = 0; r < ROWS; ++r) acc[r] = 0.f;
    #pragma unroll 4
    for (int k = 0; k < CH_IN; ++k) {
        float wv = W[k * COLS + c];
        #pragma unroll
        for (int r = 0; r < ROWS; ++r) acc[r] = fmaf(xs[r][k], wv, acc[r]);
    }
    for (int r = 0; r < ROWS; ++r) {
        int row = row0 + r;
        if (row < N) H[(size_t)row * COLS + c] = acc[r];
    }
}

// out[n][c] = b[c] + h[n][c] * dinv[n]^2   (bias + self-loop term)
template<int C>
__global__ void k_init_out(const float* __restrict__ h, const float* __restrict__ b,
                           const float* __restrict__ dinv, float* __restrict__ out, int total) {
    int i = blockIdx.x * blockDim.x + threadIdx.x;
    if (i < total) {
        int n = i / C, c = i % C;
        float di = dinv[n];
        out[i] = b[c] + h[i] * di * di;
    }
}

// per edge: out[dst] += h[src] * norm, C/4 threads per edge, float4 gather
template<int C>
__global__ void k_scatter(const int* __restrict__ ei, const float* __restrict__ norm,
                          const float* __restrict__ h, float* __restrict__ out, int E) {
    constexpr int TPE = C / 4;
    int t = blockIdx.x * blockDim.x + threadIdx.x;
    int e = t / TPE;
    if (e >= E) return;
    int j = (t & (TPE - 1)) * 4;
    int s = ei[e], d = ei[E + e];
    float nm = norm[e];
    const float4 hv = *reinterpret_cast<const float4*>(h + (size_t)s * C + j);
    float* op = out + (size_t)d * C + j;
    unsafeAtomicAdd(op + 0, hv.x * nm);
    unsafeAtomicAdd(op + 1, hv.y * nm);
    unsafeAtomicAdd(op + 2, hv.z * nm);
    unsafeAtomicAdd(op + 3, hv.w * nm);
}

// one 64-lane wave per row of 64 channels; in-place
__global__ void k_logsoftmax(float* __restrict__ out, int N) {
    int g = blockIdx.x * blockDim.x + threadIdx.x;
    int row = g >> 6;
    int lane = g & 63;
    if (row >= N) return;
    float v = out[(size_t)row * 64 + lane];
    float m = v;
    #pragma unroll
    for (int off = 32; off > 0; off >>= 1) m = fmaxf(m, __shfl_xor(m, off, 64));
    float ex = expf(v - m);
    float s = ex;
    #pragma unroll
    for (int off = 32; off > 0; off >>= 1) s += __shfl_xor(s, off, 64);
    out[(size_t)row * 64 + lane] = (v - m) - logf(s);
}

extern "C" void kernel_launch(void* const* d_in, const int* in_sizes, int n_in,
                              void* d_out, int out_size, void* d_ws, size_t ws_size,
                              hipStream_t stream) {
    const float* x  = (const float*)d_in[0];
    const int*   ei = (const int*)d_in[1];     // [2,E] int32: src = ei[e], dst = ei[E+e]
    const float* w  = (const float*)d_in[2];
    const float* W1 = (const float*)d_in[3];
    const float* b1 = (const float*)d_in[4];
    const float* W2 = (const float*)d_in[5];
    const float* b2 = (const float*)d_in[6];
    float* out = (float*)d_out;

    const int N = in_sizes[0] / CH_IN;
    const int E = in_sizes[2];

    // workspace carve (floats): dinv[N] | norm[E] | h1[N*128] | out1[N*128] | h2[N*64]
    float* ws   = (float*)d_ws;
    float* dinv = ws;                     ws += N;
    float* norm = ws;                     ws += E;
    float* h1   = ws;                     ws += (size_t)N * CH_HID;
    float* out1 = ws;                     ws += (size_t)N * CH_HID;
    float* h2   = ws;                     ws += (size_t)N * CH_OUT;

    const int B = 256;

    // 1) weighted degree incl. self-loop -> dinv
    k_fill1<<<(N + B - 1) / B, B, 0, stream>>>(dinv, N);
    k_deg<<<(E + B - 1) / B, B, 0, stream>>>(ei, w, dinv, E);
    k_dinv<<<(N + B - 1) / B, B, 0, stream>>>(dinv, N);
    k_norm<<<(E + B - 1) / B, B, 0, stream>>>(ei, w, dinv, norm, E);

    // 2) h1 = x @ W1
    {
        constexpr int ROWS = 8;
        k_gemm<CH_HID, ROWS, false><<<(N + ROWS - 1) / ROWS, CH_HID, 0, stream>>>(x, W1, h1, N);
    }

    // 3) out1 = b1 + self + scatter
    k_init_out<CH_HID><<<((size_t)N * CH_HID + B - 1) / B, B, 0, stream>>>(h1, b1, dinv, out1, N * CH_HID);
    {
        constexpr int TPE = CH_HID / 4;
        size_t threads = (size_t)E * TPE;
        k_scatter<CH_HID><<<(threads + B - 1) / B, B, 0, stream>>>(ei, norm, h1, out1, E);
    }

    // 4) h2 = relu(out1) @ W2
    {
        constexpr int ROWS = 8;
        k_gemm<CH_OUT, ROWS, true><<<(N + ROWS - 1) / ROWS, CH_OUT, 0, stream>>>(out1, W2, h2, N);
    }

    // 5) out = b2 + self + scatter (accumulate directly in d_out)
    k_init_out<CH_OUT><<<((size_t)N * CH_OUT + B - 1) / B, B, 0, stream>>>(h2, b2, dinv, out, N * CH_OUT);
    {
        constexpr int TPE = CH_OUT / 4;
        size_t threads = (size_t)E * TPE;
        k_scatter<CH_OUT><<<(threads + B - 1) / B, B, 0, stream>>>(ei, norm, h2, out, E);
    }

    // 6) log_softmax rows of 64, in place on d_out
    k_logsoftmax<<<((size_t)N * 64 + B - 1) / B, B, 0, stream>>>(out, N);
}

// Round 2
// 429.677 us; speedup vs baseline: 5.0473x; 5.0473x over previous
//
#include <hip/hip_runtime.h>
#include <math.h>

static constexpr int CH_IN  = 128;
static constexpr int CH_HID = 128;
static constexpr int CH_OUT = 64;

// ---------- small utility kernels ----------

__global__ void k_zero_i(int* __restrict__ p, int n) {
    int i = blockIdx.x * blockDim.x + threadIdx.x;
    if (i < n) p[i] = 0;
}

__global__ void k_fill1(float* __restrict__ p, int n) {
    int i = blockIdx.x * blockDim.x + threadIdx.x;
    if (i < n) p[i] = 1.0f;   // self-loop weight
}

__global__ void k_deg(const int* __restrict__ ei, const float* __restrict__ w,
                      float* __restrict__ deg, int E) {
    int e = blockIdx.x * blockDim.x + threadIdx.x;
    if (e < E) unsafeAtomicAdd(&deg[ei[E + e]], w[e]);   // weighted in-degree at dst
}

__global__ void k_dinv(float* __restrict__ deg, int n) {
    int i = blockIdx.x * blockDim.x + threadIdx.x;
    if (i < n) {
        float d = deg[i];
        deg[i] = d > 0.f ? rsqrtf(d) : 0.f;   // in-place: deg -> dinv
    }
}

// histogram of dst
__global__ void k_hist(const int* __restrict__ ei, int* __restrict__ cnt, int E) {
    int e = blockIdx.x * blockDim.x + threadIdx.x;
    if (e < E) atomicAdd(&cnt[ei[E + e]], 1);
}

// single-block chunked exclusive scan: rowptr[0]=0, rowptr[i+1]=sum(cnt[0..i])
__global__ void k_scan(const int* __restrict__ cnt, int* __restrict__ rowptr, int N) {
    __shared__ int wsum[16];
    __shared__ int chunk_total;
    const int lane = threadIdx.x & 63, wid = threadIdx.x >> 6;
    int running = 0;
    if (threadIdx.x == 0) rowptr[0] = 0;
    for (int base = 0; base < N; base += 1024) {
        int i = base + threadIdx.x;
        int v = (i < N) ? cnt[i] : 0;
        int s = v;
        #pragma unroll
        for (int off = 1; off < 64; off <<= 1) {
            int t = __shfl_up(s, off, 64);
            if (lane >= off) s += t;
        }
        if (lane == 63) wsum[wid] = s;
        __syncthreads();
        if (wid == 0) {
            int wv = (lane < 16) ? wsum[lane] : 0;
            int ss = wv;
            #pragma unroll
            for (int off = 1; off < 16; off <<= 1) {
                int t = __shfl_up(ss, off, 64);
                if (lane >= off) ss += t;
            }
            if (lane < 16) wsum[lane] = ss - wv;   // exclusive wave offset
            if (lane == 15) chunk_total = ss;
        }
        __syncthreads();
        if (i < N) rowptr[i + 1] = running + s + wsum[wid];
        running += chunk_total;
        __syncthreads();   // protect wsum/chunk_total before next iteration
    }
}

// scatter edges into CSR slots; norm computed inline
__global__ void k_fill_csr(const int* __restrict__ ei, const float* __restrict__ w,
                           const float* __restrict__ dinv, const int* __restrict__ rowptr,
                           int* __restrict__ cursor, int* __restrict__ esrc,
                           float* __restrict__ enorm, int E) {
    int e = blockIdx.x * blockDim.x + threadIdx.x;
    if (e < E) {
        int s = ei[e], d = ei[E + e];
        int pos = rowptr[d] + atomicAdd(&cursor[d], 1);
        esrc[pos] = s;
        enorm[pos] = dinv[s] * w[e] * dinv[d];
    }
}

// ---------- fp32 GEMM, register-tiled over rows ----------

template<int COLS, int ROWS, bool RELU_IN>
__global__ void k_gemm(const float* __restrict__ X, const float* __restrict__ W,
                       float* __restrict__ H, int N) {
    __shared__ float xs[ROWS][CH_IN];
    const int c = threadIdx.x;
    const int row0 = blockIdx.x * ROWS;
    for (int r = 0; r < ROWS; ++r) {
        int row = row0 + r;
        if (row < N) {
            for (int i = c; i < CH_IN; i += COLS) {
                float v = X[(size_t)row * CH_IN + i];
                if (RELU_IN) v = fmaxf(v, 0.f);
                xs[r][i] = v;
            }
        }
    }
    __syncthreads();
    float acc[ROWS];
    #pragma unroll
    for (int r = 0; r < ROWS; ++r) acc[r] = 0.f;
    #pragma unroll 4
    for (int k = 0; k < CH_IN; ++k) {
        float wv = W[k * COLS + c];
        #pragma unroll
        for (int r = 0; r < ROWS; ++r) acc[r] = fmaf(xs[r][k], wv, acc[r]);
    }
    for (int r = 0; r < ROWS; ++r) {
        int row = row0 + r;
        if (row < N) H[(size_t)row * COLS + c] = acc[r];
    }
}

// ---------- CSR aggregation: one wave per node, register accumulate ----------
// out[n][:] = b + h[n]*dinv[n]^2 + sum_{e in CSR[n]} h[esrc[e]] * enorm[e]
// C=128: lane owns float2 (channels 2*lane, 2*lane+1). C=64: lane owns 1 float.

template<int C>
__global__ void k_agg(const int* __restrict__ rowptr, const int* __restrict__ esrc,
                      const float* __restrict__ enorm, const float* __restrict__ h,
                      const float* __restrict__ b, const float* __restrict__ dinv,
                      float* __restrict__ out, int N) {
    const int wave = (blockIdx.x * blockDim.x + threadIdx.x) >> 6;
    const int lane = threadIdx.x & 63;
    if (wave >= N) return;
    const int node = wave;
    const int beg = rowptr[node], end = rowptr[node + 1];

    if (C == 128) {
        const float2* hp = (const float2*)h;
        float2 acc = make_float2(0.f, 0.f);
        for (int i = beg; i < end; ++i) {
            int s = esrc[i];
            float nm = enorm[i];
            float2 hv = hp[(size_t)s * 64 + lane];
            acc.x = fmaf(hv.x, nm, acc.x);
            acc.y = fmaf(hv.y, nm, acc.y);
        }
        float di = dinv[node], sl = di * di;
        float2 hn = hp[(size_t)node * 64 + lane];
        const float2 bv = ((const float2*)b)[lane];
        acc.x = fmaf(hn.x, sl, acc.x) + bv.x;
        acc.y = fmaf(hn.y, sl, acc.y) + bv.y;
        ((float2*)out)[(size_t)node * 64 + lane] = acc;
    } else {
        float acc = 0.f;
        for (int i = beg; i < end; ++i) {
            int s = esrc[i];
            float nm = enorm[i];
            acc = fmaf(h[(size_t)s * C + lane], nm, acc);
        }
        float di = dinv[node], sl = di * di;
        acc = fmaf(h[(size_t)node * C + lane], sl, acc) + b[lane];
        out[(size_t)node * C + lane] = acc;
    }
}

// one 64-lane wave per row of 64 channels; in-place
__global__ void k_logsoftmax(float* __restrict__ out, int N) {
    int g = blockIdx.x * blockDim.x + threadIdx.x;
    int row = g >> 6;
    int lane = g & 63;
    if (row >= N) return;
    float v = out[(size_t)row * 64 + lane];
    float m = v;
    #pragma unroll
    for (int off = 32; off > 0; off >>= 1) m = fmaxf(m, __shfl_xor(m, off, 64));
    float ex = expf(v - m);
    float s = ex;
    #pragma unroll
    for (int off = 32; off > 0; off >>= 1) s += __shfl_xor(s, off, 64);
    out[(size_t)row * 64 + lane] = (v - m) - logf(s);
}

extern "C" void kernel_launch(void* const* d_in, const int* in_sizes, int n_in,
                              void* d_out, int out_size, void* d_ws, size_t ws_size,
                              hipStream_t stream) {
    const float* x  = (const float*)d_in[0];
    const int*   ei = (const int*)d_in[1];     // [2,E]: src = ei[e], dst = ei[E+e]
    const float* w  = (const float*)d_in[2];
    const float* W1 = (const float*)d_in[3];
    const float* b1 = (const float*)d_in[4];
    const float* W2 = (const float*)d_in[5];
    const float* b2 = (const float*)d_in[6];
    float* out = (float*)d_out;

    const int N = in_sizes[0] / CH_IN;
    const int E = in_sizes[2];

    // workspace carve (4-byte units, keep every block 8B-aligned):
    float* ws    = (float*)d_ws;
    float* dinv  = ws;               ws += N;            // N even
    int*   rowptr= (int*)ws;         ws += (N + 2);      // pad to even
    int*   cursor= (int*)ws;         ws += N;
    int*   esrc  = (int*)ws;         ws += E;
    float* enorm = ws;               ws += E;
    float* h1    = ws;               ws += (size_t)N * CH_HID;
    float* out1  = ws;               ws += (size_t)N * CH_HID;
    float* h2    = ws;               ws += (size_t)N * CH_OUT;

    const int B = 256;

    // 1) weighted degree incl. self-loop -> dinv
    k_fill1<<<(N + B - 1) / B, B, 0, stream>>>(dinv, N);
    k_deg<<<(E + B - 1) / B, B, 0, stream>>>(ei, w, dinv, E);
    k_dinv<<<(N + B - 1) / B, B, 0, stream>>>(dinv, N);

    // 2) CSR by dst: hist -> scan -> fill (norm computed inline)
    k_zero_i<<<(N + B - 1) / B, B, 0, stream>>>(cursor, N);
    k_hist<<<(E + B - 1) / B, B, 0, stream>>>(ei, cursor, E);
    k_scan<<<1, 1024, 0, stream>>>(cursor, rowptr, N);
    k_zero_i<<<(N + B - 1) / B, B, 0, stream>>>(cursor, N);
    k_fill_csr<<<(E + B - 1) / B, B, 0, stream>>>(ei, w, dinv, rowptr, cursor, esrc, enorm, E);

    // 3) h1 = x @ W1
    {
        constexpr int ROWS = 8;
        k_gemm<CH_HID, ROWS, false><<<(N + ROWS - 1) / ROWS, CH_HID, 0, stream>>>(x, W1, h1, N);
    }

    // 4) out1 = b1 + self + neighbor-aggregate (no atomics)
    k_agg<CH_HID><<<(N * 64 + B - 1) / B, B, 0, stream>>>(rowptr, esrc, enorm, h1, b1, dinv, out1, N);

    // 5) h2 = relu(out1) @ W2
    {
        constexpr int ROWS = 8;
        k_gemm<CH_OUT, ROWS, true><<<(N + ROWS - 1) / ROWS, CH_OUT, 0, stream>>>(out1, W2, h2, N);
    }

    // 6) out = b2 + self + aggregate, directly into d_out
    k_agg<CH_OUT><<<(N * 64 + B - 1) / B, B, 0, stream>>>(rowptr, esrc, enorm, h2, b2, dinv, out, N);

    // 7) log_softmax rows of 64, in place
    k_logsoftmax<<<((size_t)N * 64 + B - 1) / B, B, 0, stream>>>(out, N);
}

// Round 3
// 314.673 us; speedup vs baseline: 6.8920x; 1.3655x over previous
//
#include <hip/hip_runtime.h>
#include <math.h>

static constexpr int CH_IN  = 128;
static constexpr int CH_HID = 128;
static constexpr int CH_OUT = 64;

// ---------- init / degree ----------

__global__ void k_init(float* __restrict__ dinv, int* __restrict__ cursor, int n) {
    int i = blockIdx.x * blockDim.x + threadIdx.x;
    if (i < n) { dinv[i] = 1.0f; cursor[i] = 0; }   // self-loop weight; zero hist
}

// weighted in-degree (float) + edge count (int) per dst, one pass
__global__ void k_deg_hist(const int* __restrict__ ei, const float* __restrict__ w,
                           float* __restrict__ deg, int* __restrict__ cnt, int E) {
    int e = blockIdx.x * blockDim.x + threadIdx.x;
    if (e < E) {
        int d = ei[E + e];
        unsafeAtomicAdd(&deg[d], w[e]);
        atomicAdd(&cnt[d], 1);
    }
}

__global__ void k_dinv(float* __restrict__ deg, int n) {
    int i = blockIdx.x * blockDim.x + threadIdx.x;
    if (i < n) {
        float d = deg[i];
        deg[i] = d > 0.f ? rsqrtf(d) : 0.f;   // in-place: deg -> dinv
    }
}

// ---------- 3-phase exclusive scan: rowptr[i+1] = sum(cnt[0..i]) ----------

__device__ __forceinline__ int block_incl_scan_256(int v, int lane, int wid) {
    __shared__ int wtot[4];
    int s = v;
    #pragma unroll
    for (int off = 1; off < 64; off <<= 1) {
        int t = __shfl_up(s, off, 64);
        if (lane >= off) s += t;
    }
    if (lane == 63) wtot[wid] = s;
    __syncthreads();
    int woff = 0;
    for (int j = 0; j < wid; ++j) woff += wtot[j];
    return s + woff;
}

// phase 1: per-block (256 elems) inclusive scan into rowptr[i+1], block sum to bsum
__global__ void k_scan_pre(const int* __restrict__ cnt, int* __restrict__ rowptr,
                           int* __restrict__ bsum, int N) {
    const int tid = threadIdx.x, lane = tid & 63, wid = tid >> 6;
    const int i = blockIdx.x * 256 + tid;
    int v = (i < N) ? cnt[i] : 0;
    int s = block_incl_scan_256(v, lane, wid);
    if (i < N) rowptr[i + 1] = s;
    if (tid == 255) bsum[blockIdx.x] = s;
}

// phase 2: one block scans block sums exclusively in place (nb <= 256)
__global__ void k_scan_mid(int* __restrict__ bsum, int nb) {
    const int tid = threadIdx.x, lane = tid & 63, wid = tid >> 6;
    int v = (tid < nb) ? bsum[tid] : 0;
    int s = block_incl_scan_256(v, lane, wid);
    if (tid < nb) bsum[tid] = s - v;   // exclusive
}

// phase 3: add block offsets; also rowptr[0]=0 and re-zero cursor for fill pass
__global__ void k_scan_add(int* __restrict__ rowptr, const int* __restrict__ bsum,
                           int* __restrict__ cursor, int N) {
    int i = blockIdx.x * blockDim.x + threadIdx.x;
    if (i < N) {
        rowptr[i + 1] += bsum[i >> 8];
        cursor[i] = 0;
        if (i == 0) rowptr[0] = 0;
    }
}

// scatter edges into CSR slots; norm computed inline
__global__ void k_fill_csr(const int* __restrict__ ei, const float* __restrict__ w,
                           const float* __restrict__ dinv, const int* __restrict__ rowptr,
                           int* __restrict__ cursor, int* __restrict__ esrc,
                           float* __restrict__ enorm, int E) {
    int e = blockIdx.x * blockDim.x + threadIdx.x;
    if (e < E) {
        int s = ei[e], d = ei[E + e];
        int pos = rowptr[d] + atomicAdd(&cursor[d], 1);
        esrc[pos] = s;
        enorm[pos] = dinv[s] * w[e] * dinv[d];
    }
}

// ---------- fp32 GEMM: 64 rows/block, full K=128 in LDS, thread = 8 rows x TC cols ----------
// X:[N,128] (RELU optional) @ W:[128,COLS] -> H:[N,COLS].
// 256 threads: tx=tid&31 (cols, TC each), ty=tid>>5 (8 row-groups of 8).
// Per 4-k step: 8x ds_read_b128 (x) + 4 vector W loads (L1-hot) -> 8*TC*4 FMAs.

template<int COLS, bool RELU_IN>
__global__ void k_gemm(const float* __restrict__ X, const float* __restrict__ W,
                       float* __restrict__ H, int N) {
    constexpr int TC = COLS / 32;          // 4 (COLS=128) or 2 (COLS=64)
    __shared__ float xs[64 * CH_IN];
    const int tid = threadIdx.x;
    const int tx = tid & 31, ty = tid >> 5;
    const int row0 = blockIdx.x * 64;

    // stage 64 x-rows (zero-padded past N), float4-coalesced
    #pragma unroll
    for (int j = 0; j < 8; ++j) {
        int f = j * 256 + tid;             // float4 index within tile (2048 total)
        int row = f >> 5;                  // f*4/128
        int col = (f & 31) * 4;
        float4 v = make_float4(0.f, 0.f, 0.f, 0.f);
        if (row0 + row < N) {
            v = *reinterpret_cast<const float4*>(X + (size_t)(row0 + row) * CH_IN + col);
            if (RELU_IN) {
                v.x = fmaxf(v.x, 0.f); v.y = fmaxf(v.y, 0.f);
                v.z = fmaxf(v.z, 0.f); v.w = fmaxf(v.w, 0.f);
            }
        }
        *reinterpret_cast<float4*>(&xs[f * 4]) = v;
    }
    __syncthreads();

    const int rb = ty * 8;                 // this thread's first row in tile
    const int cb = tx * TC;                // this thread's first col
    float acc[8][TC];
    #pragma unroll
    for (int r = 0; r < 8; ++r)
        #pragma unroll
        for (int c = 0; c < TC; ++c) acc[r][c] = 0.f;

    for (int k0 = 0; k0 < CH_IN; k0 += 4) {
        float4 xv[8];
        #pragma unroll
        for (int r = 0; r < 8; ++r)
            xv[r] = *reinterpret_cast<const float4*>(&xs[(rb + r) * CH_IN + k0]);
        float wv[4][TC];
        #pragma unroll
        for (int kk = 0; kk < 4; ++kk) {
            if (TC == 4) {
                float4 t = *reinterpret_cast<const float4*>(W + (size_t)(k0 + kk) * COLS + cb);
                wv[kk][0] = t.x; wv[kk][1] = t.y; wv[kk][2] = t.z; wv[kk][3] = t.w;
            } else {
                float2 t = *reinterpret_cast<const float2*>(W + (size_t)(k0 + kk) * COLS + cb);
                wv[kk][0] = t.x; wv[kk][1] = t.y;
            }
        }
        #pragma unroll
        for (int kk = 0; kk < 4; ++kk) {
            #pragma unroll
            for (int r = 0; r < 8; ++r) {
                float xk = reinterpret_cast<const float*>(&xv[r])[kk];
                #pragma unroll
                for (int c = 0; c < TC; ++c)
                    acc[r][c] = fmaf(xk, wv[kk][c], acc[r][c]);
            }
        }
    }

    #pragma unroll
    for (int r = 0; r < 8; ++r) {
        int row = row0 + rb + r;
        if (row < N) {
            if (TC == 4) {
                float4 o = make_float4(acc[r][0], acc[r][1], acc[r][2], acc[r][3]);
                *reinterpret_cast<float4*>(H + (size_t)row * COLS + cb) = o;
            } else {
                float2 o = make_float2(acc[r][0], acc[r][1]);
                *reinterpret_cast<float2*>(H + (size_t)row * COLS + cb) = o;
            }
        }
    }
}

// ---------- CSR aggregation: one wave per node, 4-edge ILP ----------
// out[n][:] = b + h[n]*dinv[n]^2 + sum_{e in CSR[n]} h[esrc[e]] * enorm[e]

template<int C>
__global__ void k_agg(const int* __restrict__ rowptr, const int* __restrict__ esrc,
                      const float* __restrict__ enorm, const float* __restrict__ h,
                      const float* __restrict__ b, const float* __restrict__ dinv,
                      float* __restrict__ out, int N) {
    const int node = (blockIdx.x * blockDim.x + threadIdx.x) >> 6;
    const int lane = threadIdx.x & 63;
    if (node >= N) return;
    const int beg = rowptr[node], end = rowptr[node + 1];

    if (C == 128) {
        const float2* hp = (const float2*)h;
        float2 a0{0.f,0.f}, a1{0.f,0.f}, a2{0.f,0.f}, a3{0.f,0.f};
        int i = beg;
        for (; i + 4 <= end; i += 4) {
            int s0 = esrc[i], s1 = esrc[i+1], s2 = esrc[i+2], s3 = esrc[i+3];
            float n0 = enorm[i], n1 = enorm[i+1], n2 = enorm[i+2], n3 = enorm[i+3];
            float2 h0 = hp[(size_t)s0 * 64 + lane];
            float2 h1 = hp[(size_t)s1 * 64 + lane];
            float2 h2 = hp[(size_t)s2 * 64 + lane];
            float2 h3 = hp[(size_t)s3 * 64 + lane];
            a0.x = fmaf(h0.x, n0, a0.x); a0.y = fmaf(h0.y, n0, a0.y);
            a1.x = fmaf(h1.x, n1, a1.x); a1.y = fmaf(h1.y, n1, a1.y);
            a2.x = fmaf(h2.x, n2, a2.x); a2.y = fmaf(h2.y, n2, a2.y);
            a3.x = fmaf(h3.x, n3, a3.x); a3.y = fmaf(h3.y, n3, a3.y);
        }
        for (; i < end; ++i) {
            int s = esrc[i]; float nm = enorm[i];
            float2 hv = hp[(size_t)s * 64 + lane];
            a0.x = fmaf(hv.x, nm, a0.x); a0.y = fmaf(hv.y, nm, a0.y);
        }
        float di = dinv[node], sl = di * di;
        float2 hn = hp[(size_t)node * 64 + lane];
        const float2 bv = ((const float2*)b)[lane];
        float ox = a0.x + a1.x + a2.x + a3.x + fmaf(hn.x, sl, bv.x);
        float oy = a0.y + a1.y + a2.y + a3.y + fmaf(hn.y, sl, bv.y);
        ((float2*)out)[(size_t)node * 64 + lane] = make_float2(ox, oy);
    } else {
        float a0 = 0.f, a1 = 0.f, a2 = 0.f, a3 = 0.f;
        int i = beg;
        for (; i + 4 <= end; i += 4) {
            int s0 = esrc[i], s1 = esrc[i+1], s2 = esrc[i+2], s3 = esrc[i+3];
            float n0 = enorm[i], n1 = enorm[i+1], n2 = enorm[i+2], n3 = enorm[i+3];
            float h0 = h[(size_t)s0 * C + lane];
            float h1 = h[(size_t)s1 * C + lane];
            float h2 = h[(size_t)s2 * C + lane];
            float h3 = h[(size_t)s3 * C + lane];
            a0 = fmaf(h0, n0, a0); a1 = fmaf(h1, n1, a1);
            a2 = fmaf(h2, n2, a2); a3 = fmaf(h3, n3, a3);
        }
        for (; i < end; ++i)
            a0 = fmaf(h[(size_t)esrc[i] * C + lane], enorm[i], a0);
        float di = dinv[node], sl = di * di;
        float acc = a0 + a1 + a2 + a3 + fmaf(h[(size_t)node * C + lane], sl, b[lane]);
        out[(size_t)node * C + lane] = acc;
    }
}

// one 64-lane wave per row of 64 channels; in-place
__global__ void k_logsoftmax(float* __restrict__ out, int N) {
    int g = blockIdx.x * blockDim.x + threadIdx.x;
    int row = g >> 6;
    int lane = g & 63;
    if (row >= N) return;
    float v = out[(size_t)row * 64 + lane];
    float m = v;
    #pragma unroll
    for (int off = 32; off > 0; off >>= 1) m = fmaxf(m, __shfl_xor(m, off, 64));
    float ex = expf(v - m);
    float s = ex;
    #pragma unroll
    for (int off = 32; off > 0; off >>= 1) s += __shfl_xor(s, off, 64);
    out[(size_t)row * 64 + lane] = (v - m) - logf(s);
}

extern "C" void kernel_launch(void* const* d_in, const int* in_sizes, int n_in,
                              void* d_out, int out_size, void* d_ws, size_t ws_size,
                              hipStream_t stream) {
    const float* x  = (const float*)d_in[0];
    const int*   ei = (const int*)d_in[1];     // [2,E]: src = ei[e], dst = ei[E+e]
    const float* w  = (const float*)d_in[2];
    const float* W1 = (const float*)d_in[3];
    const float* b1 = (const float*)d_in[4];
    const float* W2 = (const float*)d_in[5];
    const float* b2 = (const float*)d_in[6];
    float* out = (float*)d_out;

    const int N = in_sizes[0] / CH_IN;
    const int E = in_sizes[2];
    const int NB = (N + 255) / 256;            // scan blocks (196 <= 256)

    // workspace carve (4-byte units; keep float2 arrays 8B-aligned)
    float* ws    = (float*)d_ws;
    float* dinv  = ws;               ws += N;            // 50000
    int*   rowptr= (int*)ws;         ws += (N + 2);      // 50002
    int*   cursor= (int*)ws;         ws += N;            // 50000
    int*   bsum  = (int*)ws;         ws += 256;          // scan block sums
    int*   esrc  = (int*)ws;         ws += E;
    float* enorm = ws;               ws += E;             // running total even
    float* h1    = ws;               ws += (size_t)N * CH_HID;
    float* out1  = ws;               ws += (size_t)N * CH_HID;
    float* h2    = ws;               ws += (size_t)N * CH_OUT;

    const int B = 256;

    // 1) degree + histogram in one pass
    k_init<<<(N + B - 1) / B, B, 0, stream>>>(dinv, cursor, N);
    k_deg_hist<<<(E + B - 1) / B, B, 0, stream>>>(ei, w, dinv, cursor, E);
    k_dinv<<<(N + B - 1) / B, B, 0, stream>>>(dinv, N);

    // 2) rowptr = exclusive-scan(cnt), 3-phase; re-zeros cursor
    k_scan_pre<<<NB, 256, 0, stream>>>(cursor, rowptr, bsum, N);
    k_scan_mid<<<1, 256, 0, stream>>>(bsum, NB);
    k_scan_add<<<(N + B - 1) / B, B, 0, stream>>>(rowptr, bsum, cursor, N);
    k_fill_csr<<<(E + B - 1) / B, B, 0, stream>>>(ei, w, dinv, rowptr, cursor, esrc, enorm, E);

    // 3) h1 = x @ W1
    k_gemm<CH_HID, false><<<(N + 63) / 64, 256, 0, stream>>>(x, W1, h1, N);

    // 4) out1 = b1 + self + neighbor aggregate
    k_agg<CH_HID><<<(N * 64 + B - 1) / B, B, 0, stream>>>(rowptr, esrc, enorm, h1, b1, dinv, out1, N);

    // 5) h2 = relu(out1) @ W2
    k_gemm<CH_OUT, true><<<(N + 63) / 64, 256, 0, stream>>>(out1, W2, h2, N);

    // 6) out = b2 + self + aggregate, directly into d_out
    k_agg<CH_OUT><<<(N * 64 + B - 1) / B, B, 0, stream>>>(rowptr, esrc, enorm, h2, b2, dinv, out, N);

    // 7) log_softmax rows of 64, in place
    k_logsoftmax<<<((size_t)N * 64 + B - 1) / B, B, 0, stream>>>(out, N);
}

// Round 5
// 239.537 us; speedup vs baseline: 9.0538x; 1.3137x over previous
//
#include <hip/hip_runtime.h>
#include <math.h>

static constexpr int CH_IN  = 128;
static constexpr int CH_HID = 128;
static constexpr int CH_OUT = 64;

// ---------- CSR build (single atomic pass) ----------

__global__ void k_zero_i(int* __restrict__ p, int n) {
    int i = blockIdx.x * blockDim.x + threadIdx.x;
    if (i < n) p[i] = 0;
}

// histogram of dst; returned old value = within-row ordinal -> eord
__global__ void k_hist(const int* __restrict__ ei, int* __restrict__ cnt,
                       int* __restrict__ eord, int E) {
    int e = blockIdx.x * blockDim.x + threadIdx.x;
    if (e < E) eord[e] = atomicAdd(&cnt[ei[E + e]], 1);
}

// ---------- 3-phase exclusive scan: rowptr[i+1] = sum(cnt[0..i]) ----------

__device__ __forceinline__ int block_incl_scan_256(int v, int lane, int wid) {
    __shared__ int wtot[4];
    int s = v;
    #pragma unroll
    for (int off = 1; off < 64; off <<= 1) {
        int t = __shfl_up(s, off, 64);
        if (lane >= off) s += t;
    }
    if (lane == 63) wtot[wid] = s;
    __syncthreads();
    int woff = 0;
    for (int j = 0; j < wid; ++j) woff += wtot[j];
    return s + woff;
}

__global__ void k_scan_pre(const int* __restrict__ cnt, int* __restrict__ rowptr,
                           int* __restrict__ bsum, int N) {
    const int tid = threadIdx.x, lane = tid & 63, wid = tid >> 6;
    const int i = blockIdx.x * 256 + tid;
    int v = (i < N) ? cnt[i] : 0;
    int s = block_incl_scan_256(v, lane, wid);
    if (i < N) rowptr[i + 1] = s;
    if (tid == 255) bsum[blockIdx.x] = s;
}

__global__ void k_scan_mid(int* __restrict__ bsum, int nb) {
    const int tid = threadIdx.x, lane = tid & 63, wid = tid >> 6;
    int v = (tid < nb) ? bsum[tid] : 0;
    int s = block_incl_scan_256(v, lane, wid);
    if (tid < nb) bsum[tid] = s - v;   // exclusive
}

__global__ void k_scan_add(int* __restrict__ rowptr, const int* __restrict__ bsum, int N) {
    int i = blockIdx.x * blockDim.x + threadIdx.x;
    if (i < N) {
        rowptr[i + 1] += bsum[i >> 8];
        if (i == 0) rowptr[0] = 0;
    }
}

// atomic-free fill: pos = rowptr[dst] + eord[e]; epack = {src, bits(w)}
__global__ void k_fill(const int* __restrict__ ei, const float* __restrict__ w,
                       const int* __restrict__ eord, const int* __restrict__ rowptr,
                       int2* __restrict__ epack, int E) {
    int e = blockIdx.x * blockDim.x + threadIdx.x;
    if (e < E) {
        int d = ei[E + e];
        int pos = rowptr[d] + eord[e];
        epack[pos] = make_int2(ei[e], __float_as_int(w[e]));
    }
}

// dinv[n] = rsqrt(1 + sum of row weights)  (self-loop weight 1 included)
__global__ void k_degdinv(const int* __restrict__ rowptr, const int2* __restrict__ epack,
                          float* __restrict__ dinv, int N) {
    int n = blockIdx.x * blockDim.x + threadIdx.x;
    if (n >= N) return;
    int beg = rowptr[n], end = rowptr[n + 1];
    float s = 1.0f;
    for (int i = beg; i < end; ++i) s += __int_as_float(epack[i].y);
    dinv[n] = rsqrtf(s);
}

// ---------- fp32 GEMM: 64 rows/block, full K=128 in LDS, thread = 8 rows x TC cols ----------

template<int COLS, bool RELU_IN>
__global__ void k_gemm(const float* __restrict__ X, const float* __restrict__ W,
                       float* __restrict__ H, int N) {
    constexpr int TC = COLS / 32;          // 4 (COLS=128) or 2 (COLS=64)
    __shared__ float xs[64 * CH_IN];
    const int tid = threadIdx.x;
    const int tx = tid & 31, ty = tid >> 5;
    const int row0 = blockIdx.x * 64;

    #pragma unroll
    for (int j = 0; j < 8; ++j) {
        int f = j * 256 + tid;             // float4 index within tile
        int row = f >> 5;
        int col = (f & 31) * 4;
        float4 v = make_float4(0.f, 0.f, 0.f, 0.f);
        if (row0 + row < N) {
            v = *reinterpret_cast<const float4*>(X + (size_t)(row0 + row) * CH_IN + col);
            if (RELU_IN) {
                v.x = fmaxf(v.x, 0.f); v.y = fmaxf(v.y, 0.f);
                v.z = fmaxf(v.z, 0.f); v.w = fmaxf(v.w, 0.f);
            }
        }
        *reinterpret_cast<float4*>(&xs[f * 4]) = v;
    }
    __syncthreads();

    const int rb = ty * 8;
    const int cb = tx * TC;
    float acc[8][TC];
    #pragma unroll
    for (int r = 0; r < 8; ++r)
        #pragma unroll
        for (int c = 0; c < TC; ++c) acc[r][c] = 0.f;

    for (int k0 = 0; k0 < CH_IN; k0 += 4) {
        float4 xv[8];
        #pragma unroll
        for (int r = 0; r < 8; ++r)
            xv[r] = *reinterpret_cast<const float4*>(&xs[(rb + r) * CH_IN + k0]);
        float wv[4][TC];
        #pragma unroll
        for (int kk = 0; kk < 4; ++kk) {
            if (TC == 4) {
                float4 t = *reinterpret_cast<const float4*>(W + (size_t)(k0 + kk) * COLS + cb);
                wv[kk][0] = t.x; wv[kk][1] = t.y; wv[kk][2] = t.z; wv[kk][3] = t.w;
            } else {
                float2 t = *reinterpret_cast<const float2*>(W + (size_t)(k0 + kk) * COLS + cb);
                wv[kk][0] = t.x; wv[kk][1] = t.y;
            }
        }
        #pragma unroll
        for (int kk = 0; kk < 4; ++kk) {
            #pragma unroll
            for (int r = 0; r < 8; ++r) {
                float xk = reinterpret_cast<const float*>(&xv[r])[kk];
                #pragma unroll
                for (int c = 0; c < TC; ++c)
                    acc[r][c] = fmaf(xk, wv[kk][c], acc[r][c]);
            }
        }
    }

    #pragma unroll
    for (int r = 0; r < 8; ++r) {
        int row = row0 + rb + r;
        if (row < N) {
            if (TC == 4) {
                float4 o = make_float4(acc[r][0], acc[r][1], acc[r][2], acc[r][3]);
                *reinterpret_cast<float4*>(H + (size_t)row * COLS + cb) = o;
            } else {
                float2 o = make_float2(acc[r][0], acc[r][1]);
                *reinterpret_cast<float2*>(H + (size_t)row * COLS + cb) = o;
            }
        }
    }
}

// ---------- CSR aggregation v3: wave per node, cooperative metadata, ILP8 ----------
// out[n][:] = b + h[n]*dinv[n]^2 + dinv[n] * sum_e h[src_e] * (w_e * dinv[src_e])

template<int C, bool SOFTMAX>
__global__ void k_agg(const int* __restrict__ rowptr, const int2* __restrict__ epack,
                      const float* __restrict__ dinv, const float* __restrict__ h,
                      const float* __restrict__ b, float* __restrict__ out, int N) {
    const int node = (blockIdx.x * blockDim.x + threadIdx.x) >> 6;
    const int lane = threadIdx.x & 63;
    if (node >= N) return;
    const int beg = rowptr[node], end = rowptr[node + 1];
    const float dd = dinv[node];

    if (C == 128) {
        const float2* hp = (const float2*)h;
        float2 a[8];
        #pragma unroll
        for (int k = 0; k < 8; ++k) a[k] = make_float2(0.f, 0.f);

        for (int i0 = beg; i0 < end; i0 += 64) {
            const int m = min(64, end - i0);
            int s_l = 0; float nm_l = 0.f;
            if (lane < m) {
                int2 p = epack[i0 + lane];
                s_l = p.x;
                nm_l = __int_as_float(p.y) * dinv[p.x];   // w * dinv[src]; dst factor applied at end
            }
            int j = 0;
            for (; j + 8 <= m; j += 8) {
                #pragma unroll
                for (int k = 0; k < 8; ++k) {
                    int   s  = __shfl(s_l, j + k, 64);
                    float nm = __shfl(nm_l, j + k, 64);
                    float2 hv = hp[(size_t)s * 64 + lane];
                    a[k].x = fmaf(hv.x, nm, a[k].x);
                    a[k].y = fmaf(hv.y, nm, a[k].y);
                }
            }
            for (; j < m; ++j) {
                int   s  = __shfl(s_l, j, 64);
                float nm = __shfl(nm_l, j, 64);
                float2 hv = hp[(size_t)s * 64 + lane];
                a[0].x = fmaf(hv.x, nm, a[0].x);
                a[0].y = fmaf(hv.y, nm, a[0].y);
            }
        }
        float sx = ((a[0].x + a[1].x) + (a[2].x + a[3].x)) + ((a[4].x + a[5].x) + (a[6].x + a[7].x));
        float sy = ((a[0].y + a[1].y) + (a[2].y + a[3].y)) + ((a[4].y + a[5].y) + (a[6].y + a[7].y));
        float2 hn = hp[(size_t)node * 64 + lane];
        float2 bv = ((const float2*)b)[lane];
        // apply dst-side dinv to neighbor sum; self term gets dd^2
        sx = fmaf(sx, dd, fmaf(hn.x, dd * dd, bv.x));
        sy = fmaf(sy, dd, fmaf(hn.y, dd * dd, bv.y));
        ((float2*)out)[(size_t)node * 64 + lane] = make_float2(sx, sy);
    } else {
        float a[8];
        #pragma unroll
        for (int k = 0; k < 8; ++k) a[k] = 0.f;

        for (int i0 = beg; i0 < end; i0 += 64) {
            const int m = min(64, end - i0);
            int s_l = 0; float nm_l = 0.f;
            if (lane < m) {
                int2 p = epack[i0 + lane];
                s_l = p.x;
                nm_l = __int_as_float(p.y) * dinv[p.x];
            }
            int j = 0;
            for (; j + 8 <= m; j += 8) {
                #pragma unroll
                for (int k = 0; k < 8; ++k) {
                    int   s  = __shfl(s_l, j + k, 64);
                    float nm = __shfl(nm_l, j + k, 64);
                    a[k] = fmaf(h[(size_t)s * C + lane], nm, a[k]);
                }
            }
            for (; j < m; ++j) {
                int   s  = __shfl(s_l, j, 64);
                float nm = __shfl(nm_l, j, 64);
                a[0] = fmaf(h[(size_t)s * C + lane], nm, a[0]);
            }
        }
        float v = ((a[0] + a[1]) + (a[2] + a[3])) + ((a[4] + a[5]) + (a[6] + a[7]));
        v = fmaf(v, dd, fmaf(h[(size_t)node * C + lane], dd * dd, b[lane]));

        if (SOFTMAX) {
            float mx = v;
            #pragma unroll
            for (int off = 32; off > 0; off >>= 1) mx = fmaxf(mx, __shfl_xor(mx, off, 64));
            float ex = expf(v - mx);
            float sm = ex;
            #pragma unroll
            for (int off = 32; off > 0; off >>= 1) sm += __shfl_xor(sm, off, 64);
            out[(size_t)node * C + lane] = (v - mx) - logf(sm);
        } else {
            out[(size_t)node * C + lane] = v;
        }
    }
}

extern "C" void kernel_launch(void* const* d_in, const int* in_sizes, int n_in,
                              void* d_out, int out_size, void* d_ws, size_t ws_size,
                              hipStream_t stream) {
    const float* x  = (const float*)d_in[0];
    const int*   ei = (const int*)d_in[1];     // [2,E]: src = ei[e], dst = ei[E+e]
    const float* w  = (const float*)d_in[2];
    const float* W1 = (const float*)d_in[3];
    const float* b1 = (const float*)d_in[4];
    const float* W2 = (const float*)d_in[5];
    const float* b2 = (const float*)d_in[6];
    float* out = (float*)d_out;

    const int N = in_sizes[0] / CH_IN;
    const int E = in_sizes[2];
    const int NB = (N + 255) / 256;            // scan blocks (<= 256)

    // workspace carve (4-byte units; epack must be 8B-aligned)
    float* ws    = (float*)d_ws;
    float* dinv  = ws;               ws += N;               // N even
    int*   rowptr= (int*)ws;         ws += (N + 2);
    int*   cnt   = (int*)ws;         ws += N;
    int*   bsum  = (int*)ws;         ws += 256;
    int*   eord  = (int*)ws;         ws += E;
    int2*  epack = (int2*)ws;        ws += (size_t)2 * E;   // 8B-aligned (offset even)
    float* h1    = ws;               ws += (size_t)N * CH_HID;
    float* out1  = ws;               ws += (size_t)N * CH_HID;
    float* h2    = ws;               ws += (size_t)N * CH_OUT;

    const int B = 256;

    // 1) histogram with ordinal capture (only atomic pass)
    k_zero_i<<<(N + B - 1) / B, B, 0, stream>>>(cnt, N);
    k_hist<<<(E + B - 1) / B, B, 0, stream>>>(ei, cnt, eord, E);

    // 2) rowptr = exclusive scan(cnt); atomic-free fill; degree from CSR
    k_scan_pre<<<NB, 256, 0, stream>>>(cnt, rowptr, bsum, N);
    k_scan_mid<<<1, 256, 0, stream>>>(bsum, NB);
    k_scan_add<<<(N + B - 1) / B, B, 0, stream>>>(rowptr, bsum, N);
    k_fill<<<(E + B - 1) / B, B, 0, stream>>>(ei, w, eord, rowptr, epack, E);
    k_degdinv<<<(N + B - 1) / B, B, 0, stream>>>(rowptr, epack, dinv, N);

    // 3) h1 = x @ W1
    k_gemm<CH_HID, false><<<(N + 63) / 64, 256, 0, stream>>>(x, W1, h1, N);

    // 4) out1 = b1 + self + neighbor aggregate
    k_agg<CH_HID, false><<<(N * 64 + B - 1) / B, B, 0, stream>>>(rowptr, epack, dinv, h1, b1, out1, N);

    // 5) h2 = relu(out1) @ W2
    k_gemm<CH_OUT, true><<<(N + 63) / 64, 256, 0, stream>>>(out1, W2, h2, N);

    // 6) out = log_softmax(b2 + self + aggregate), fused, directly into d_out
    k_agg<CH_OUT, true><<<(N * 64 + B - 1) / B, B, 0, stream>>>(rowptr, epack, dinv, h2, b2, out, N);
}

// Round 6
// 198.311 us; speedup vs baseline: 10.9360x; 1.2079x over previous
//
#include <hip/hip_runtime.h>
#include <math.h>

static constexpr int CH_IN  = 128;
static constexpr int CH_HID = 128;
static constexpr int CH_OUT = 64;

// ---------- bf16 helpers (RNE pack, cheap unpack) ----------

__device__ __forceinline__ float bf2f(unsigned short u) {
    return __uint_as_float(((unsigned int)u) << 16);
}
__device__ __forceinline__ unsigned short f2bf(float f) {
    unsigned int u = __float_as_uint(f);
    u = (u + 0x7fffu + ((u >> 16) & 1u)) >> 16;   // round-to-nearest-even
    return (unsigned short)u;
}
__device__ __forceinline__ unsigned int pack2(float lo, float hi) {
    return (unsigned int)f2bf(lo) | ((unsigned int)f2bf(hi) << 16);
}
__device__ __forceinline__ void unpack2(unsigned int u, float& lo, float& hi) {
    lo = __uint_as_float(u << 16);
    hi = __uint_as_float(u & 0xffff0000u);
}

// ---------- CSR build (single atomic pass) ----------

__global__ void k_zero_i(int* __restrict__ p, int n) {
    int i = blockIdx.x * blockDim.x + threadIdx.x;
    if (i < n) p[i] = 0;
}

// histogram of dst; returned old value = within-row ordinal -> eord
__global__ void k_hist(const int* __restrict__ ei, int* __restrict__ cnt,
                       int* __restrict__ eord, int E) {
    int e = blockIdx.x * blockDim.x + threadIdx.x;
    if (e < E) eord[e] = atomicAdd(&cnt[ei[E + e]], 1);
}

// ---------- 3-phase exclusive scan: rowptr[i+1] = sum(cnt[0..i]) ----------

__device__ __forceinline__ int block_incl_scan_256(int v, int lane, int wid) {
    __shared__ int wtot[4];
    int s = v;
    #pragma unroll
    for (int off = 1; off < 64; off <<= 1) {
        int t = __shfl_up(s, off, 64);
        if (lane >= off) s += t;
    }
    if (lane == 63) wtot[wid] = s;
    __syncthreads();
    int woff = 0;
    for (int j = 0; j < wid; ++j) woff += wtot[j];
    return s + woff;
}

__global__ void k_scan_pre(const int* __restrict__ cnt, int* __restrict__ rowptr,
                           int* __restrict__ bsum, int N) {
    const int tid = threadIdx.x, lane = tid & 63, wid = tid >> 6;
    const int i = blockIdx.x * 256 + tid;
    int v = (i < N) ? cnt[i] : 0;
    int s = block_incl_scan_256(v, lane, wid);
    if (i < N) rowptr[i + 1] = s;
    if (tid == 255) bsum[blockIdx.x] = s;
}

__global__ void k_scan_mid(int* __restrict__ bsum, int nb) {
    const int tid = threadIdx.x, lane = tid & 63, wid = tid >> 6;
    int v = (tid < nb) ? bsum[tid] : 0;
    int s = block_incl_scan_256(v, lane, wid);
    if (tid < nb) bsum[tid] = s - v;   // exclusive
}

__global__ void k_scan_add(int* __restrict__ rowptr, const int* __restrict__ bsum, int N) {
    int i = blockIdx.x * blockDim.x + threadIdx.x;
    if (i < N) {
        rowptr[i + 1] += bsum[i >> 8];
        if (i == 0) rowptr[0] = 0;
    }
}

// atomic-free fill: pos = rowptr[dst] + eord[e]; epack = {src, bits(w)}
__global__ void k_fill(const int* __restrict__ ei, const float* __restrict__ w,
                       const int* __restrict__ eord, const int* __restrict__ rowptr,
                       int2* __restrict__ epack, int E) {
    int e = blockIdx.x * blockDim.x + threadIdx.x;
    if (e < E) {
        int d = ei[E + e];
        int pos = rowptr[d] + eord[e];
        epack[pos] = make_int2(ei[e], __float_as_int(w[e]));
    }
}

// dinv[n] = rsqrt(1 + sum of row weights)  (self-loop weight 1 included)
__global__ void k_degdinv(const int* __restrict__ rowptr, const int2* __restrict__ epack,
                          float* __restrict__ dinv, int N) {
    int n = blockIdx.x * blockDim.x + threadIdx.x;
    if (n >= N) return;
    int beg = rowptr[n], end = rowptr[n + 1];
    float s = 1.0f;
    for (int i = beg; i < end; ++i) s += __int_as_float(epack[i].y);
    dinv[n] = rsqrtf(s);
}

// ---------- fp32-accum GEMM, bf16 output: 64 rows/block, K=128 in LDS ----------
// TIN = float (plain) or ushort (bf16 input, optional fused ReLU on load).

template<int COLS, bool RELU_IN, typename TIN>
__global__ void k_gemm(const TIN* __restrict__ X, const float* __restrict__ W,
                       unsigned short* __restrict__ H, int N) {
    constexpr int TC = COLS / 32;          // 4 (COLS=128) or 2 (COLS=64)
    __shared__ float xs[64 * CH_IN];
    const int tid = threadIdx.x;
    const int tx = tid & 31, ty = tid >> 5;
    const int row0 = blockIdx.x * 64;

    if constexpr (sizeof(TIN) == 4) {      // fp32 input, float4 staging
        #pragma unroll
        for (int j = 0; j < 8; ++j) {
            int f = j * 256 + tid;         // float4 index within tile (2048 total)
            int row = f >> 5;
            int col = (f & 31) * 4;
            float4 v = make_float4(0.f, 0.f, 0.f, 0.f);
            if (row0 + row < N) {
                v = *reinterpret_cast<const float4*>((const float*)X + (size_t)(row0 + row) * CH_IN + col);
                if (RELU_IN) {
                    v.x = fmaxf(v.x, 0.f); v.y = fmaxf(v.y, 0.f);
                    v.z = fmaxf(v.z, 0.f); v.w = fmaxf(v.w, 0.f);
                }
            }
            *reinterpret_cast<float4*>(&xs[f * 4]) = v;
        }
    } else {                               // bf16 input, uint4 staging (8 bf16 each)
        #pragma unroll
        for (int j = 0; j < 4; ++j) {
            int f = j * 256 + tid;         // uint4 index within tile (1024 total)
            int row = f >> 4;              // 16 uint4 per 128-ch row
            int col0 = (f & 15) * 8;
            float o[8];
            #pragma unroll
            for (int q = 0; q < 8; ++q) o[q] = 0.f;
            if (row0 + row < N) {
                uint4 v = *reinterpret_cast<const uint4*>((const unsigned short*)X + (size_t)(row0 + row) * CH_IN + col0);
                unpack2(v.x, o[0], o[1]); unpack2(v.y, o[2], o[3]);
                unpack2(v.z, o[4], o[5]); unpack2(v.w, o[6], o[7]);
                if (RELU_IN) {
                    #pragma unroll
                    for (int q = 0; q < 8; ++q) o[q] = fmaxf(o[q], 0.f);
                }
            }
            #pragma unroll
            for (int q = 0; q < 8; ++q) xs[row * CH_IN + col0 + q] = o[q];
        }
    }
    __syncthreads();

    const int rb = ty * 8;
    const int cb = tx * TC;
    float acc[8][TC];
    #pragma unroll
    for (int r = 0; r < 8; ++r)
        #pragma unroll
        for (int c = 0; c < TC; ++c) acc[r][c] = 0.f;

    for (int k0 = 0; k0 < CH_IN; k0 += 4) {
        float4 xv[8];
        #pragma unroll
        for (int r = 0; r < 8; ++r)
            xv[r] = *reinterpret_cast<const float4*>(&xs[(rb + r) * CH_IN + k0]);
        float wv[4][TC];
        #pragma unroll
        for (int kk = 0; kk < 4; ++kk) {
            if (TC == 4) {
                float4 t = *reinterpret_cast<const float4*>(W + (size_t)(k0 + kk) * COLS + cb);
                wv[kk][0] = t.x; wv[kk][1] = t.y; wv[kk][2] = t.z; wv[kk][3] = t.w;
            } else {
                float2 t = *reinterpret_cast<const float2*>(W + (size_t)(k0 + kk) * COLS + cb);
                wv[kk][0] = t.x; wv[kk][1] = t.y;
            }
        }
        #pragma unroll
        for (int kk = 0; kk < 4; ++kk) {
            #pragma unroll
            for (int r = 0; r < 8; ++r) {
                float xk = reinterpret_cast<const float*>(&xv[r])[kk];
                #pragma unroll
                for (int c = 0; c < TC; ++c)
                    acc[r][c] = fmaf(xk, wv[kk][c], acc[r][c]);
            }
        }
    }

    #pragma unroll
    for (int r = 0; r < 8; ++r) {
        int row = row0 + rb + r;
        if (row < N) {
            if (TC == 4) {
                uint2 o;
                o.x = pack2(acc[r][0], acc[r][1]);
                o.y = pack2(acc[r][2], acc[r][3]);
                *reinterpret_cast<uint2*>(H + (size_t)row * COLS + cb) = o;
            } else {
                *reinterpret_cast<unsigned int*>(H + (size_t)row * COLS + cb) =
                    pack2(acc[r][0], acc[r][1]);
            }
        }
    }
}

// ---------- CSR aggregation: wave per node, cooperative metadata, bf16 gathers ----------
// out[n][:] = b + h[n]*dinv[n]^2 + dinv[n] * sum_e h[src_e] * (w_e * dinv[src_e])

// C=128: lane owns 2 channels (one uint = 2 bf16); bf16 output.
__global__ void k_agg128(const int* __restrict__ rowptr, const int2* __restrict__ epack,
                         const float* __restrict__ dinv, const unsigned short* __restrict__ h,
                         const float* __restrict__ b, unsigned short* __restrict__ out, int N) {
    const int node = (blockIdx.x * blockDim.x + threadIdx.x) >> 6;
    const int lane = threadIdx.x & 63;
    if (node >= N) return;
    const int beg = rowptr[node], end = rowptr[node + 1];
    const float dd = dinv[node];
    const unsigned int* hp = (const unsigned int*)h;   // 64 uints per row

    float2 a[8];
    #pragma unroll
    for (int k = 0; k < 8; ++k) a[k] = make_float2(0.f, 0.f);

    for (int i0 = beg; i0 < end; i0 += 64) {
        const int m = min(64, end - i0);
        int s_l = 0; float nm_l = 0.f;
        if (lane < m) {
            int2 p = epack[i0 + lane];
            s_l = p.x;
            nm_l = __int_as_float(p.y) * dinv[p.x];
        }
        int j = 0;
        for (; j + 8 <= m; j += 8) {
            #pragma unroll
            for (int k = 0; k < 8; ++k) {
                int   s  = __shfl(s_l, j + k, 64);
                float nm = __shfl(nm_l, j + k, 64);
                float lo, hi; unpack2(hp[(size_t)s * 64 + lane], lo, hi);
                a[k].x = fmaf(lo, nm, a[k].x);
                a[k].y = fmaf(hi, nm, a[k].y);
            }
        }
        for (; j + 4 <= m; j += 4) {
            #pragma unroll
            for (int k = 0; k < 4; ++k) {
                int   s  = __shfl(s_l, j + k, 64);
                float nm = __shfl(nm_l, j + k, 64);
                float lo, hi; unpack2(hp[(size_t)s * 64 + lane], lo, hi);
                a[k].x = fmaf(lo, nm, a[k].x);
                a[k].y = fmaf(hi, nm, a[k].y);
            }
        }
        for (; j < m; ++j) {
            int   s  = __shfl(s_l, j, 64);
            float nm = __shfl(nm_l, j, 64);
            float lo, hi; unpack2(hp[(size_t)s * 64 + lane], lo, hi);
            a[0].x = fmaf(lo, nm, a[0].x);
            a[0].y = fmaf(hi, nm, a[0].y);
        }
    }
    float sx = ((a[0].x + a[1].x) + (a[2].x + a[3].x)) + ((a[4].x + a[5].x) + (a[6].x + a[7].x));
    float sy = ((a[0].y + a[1].y) + (a[2].y + a[3].y)) + ((a[4].y + a[5].y) + (a[6].y + a[7].y));
    float hnl, hnh; unpack2(hp[(size_t)node * 64 + lane], hnl, hnh);
    float2 bv = ((const float2*)b)[lane];
    sx = fmaf(sx, dd, fmaf(hnl, dd * dd, bv.x));
    sy = fmaf(sy, dd, fmaf(hnh, dd * dd, bv.y));
    ((unsigned int*)out)[(size_t)node * 64 + lane] = pack2(sx, sy);
}

// C=64: lane owns 1 channel; fused log_softmax; fp32 output (d_out).
__global__ void k_agg64(const int* __restrict__ rowptr, const int2* __restrict__ epack,
                        const float* __restrict__ dinv, const unsigned short* __restrict__ h,
                        const float* __restrict__ b, float* __restrict__ out, int N) {
    const int node = (blockIdx.x * blockDim.x + threadIdx.x) >> 6;
    const int lane = threadIdx.x & 63;
    if (node >= N) return;
    const int beg = rowptr[node], end = rowptr[node + 1];
    const float dd = dinv[node];

    float a[8];
    #pragma unroll
    for (int k = 0; k < 8; ++k) a[k] = 0.f;

    for (int i0 = beg; i0 < end; i0 += 64) {
        const int m = min(64, end - i0);
        int s_l = 0; float nm_l = 0.f;
        if (lane < m) {
            int2 p = epack[i0 + lane];
            s_l = p.x;
            nm_l = __int_as_float(p.y) * dinv[p.x];
        }
        int j = 0;
        for (; j + 8 <= m; j += 8) {
            #pragma unroll
            for (int k = 0; k < 8; ++k) {
                int   s  = __shfl(s_l, j + k, 64);
                float nm = __shfl(nm_l, j + k, 64);
                a[k] = fmaf(bf2f(h[(size_t)s * 64 + lane]), nm, a[k]);
            }
        }
        for (; j + 4 <= m; j += 4) {
            #pragma unroll
            for (int k = 0; k < 4; ++k) {
                int   s  = __shfl(s_l, j + k, 64);
                float nm = __shfl(nm_l, j + k, 64);
                a[k] = fmaf(bf2f(h[(size_t)s * 64 + lane]), nm, a[k]);
            }
        }
        for (; j < m; ++j) {
            int   s  = __shfl(s_l, j, 64);
            float nm = __shfl(nm_l, j, 64);
            a[0] = fmaf(bf2f(h[(size_t)s * 64 + lane]), nm, a[0]);
        }
    }
    float v = ((a[0] + a[1]) + (a[2] + a[3])) + ((a[4] + a[5]) + (a[6] + a[7]));
    v = fmaf(v, dd, fmaf(bf2f(h[(size_t)node * 64 + lane]), dd * dd, b[lane]));

    float mx = v;
    #pragma unroll
    for (int off = 32; off > 0; off >>= 1) mx = fmaxf(mx, __shfl_xor(mx, off, 64));
    float ex = expf(v - mx);
    float sm = ex;
    #pragma unroll
    for (int off = 32; off > 0; off >>= 1) sm += __shfl_xor(sm, off, 64);
    out[(size_t)node * 64 + lane] = (v - mx) - logf(sm);
}

extern "C" void kernel_launch(void* const* d_in, const int* in_sizes, int n_in,
                              void* d_out, int out_size, void* d_ws, size_t ws_size,
                              hipStream_t stream) {
    const float* x  = (const float*)d_in[0];
    const int*   ei = (const int*)d_in[1];     // [2,E]: src = ei[e], dst = ei[E+e]
    const float* w  = (const float*)d_in[2];
    const float* W1 = (const float*)d_in[3];
    const float* b1 = (const float*)d_in[4];
    const float* W2 = (const float*)d_in[5];
    const float* b2 = (const float*)d_in[6];
    float* out = (float*)d_out;

    const int N = in_sizes[0] / CH_IN;
    const int E = in_sizes[2];
    const int NB = (N + 255) / 256;            // scan blocks (<= 256)

    // workspace carve (4-byte units; bf16 feature arrays padded to 16B alignment)
    float* ws    = (float*)d_ws;
    float* dinv  = ws;               ws += N;
    int*   rowptr= (int*)ws;         ws += (N + 2);
    int*   cnt   = (int*)ws;         ws += N;
    int*   bsum  = (int*)ws;         ws += 256;
    int*   eord  = (int*)ws;         ws += E;
    int2*  epack = (int2*)ws;        ws += (size_t)2 * E;   // 8B-aligned
    ws += ((size_t)(ws - (float*)d_ws) & 3) ? (4 - ((size_t)(ws - (float*)d_ws) & 3)) : 0; // 16B align
    unsigned short* h1   = (unsigned short*)ws;  ws += (size_t)N * CH_HID / 2;  // bf16 [N,128]
    unsigned short* out1 = (unsigned short*)ws;  ws += (size_t)N * CH_HID / 2;  // bf16 [N,128]
    unsigned short* h2   = (unsigned short*)ws;  ws += (size_t)N * CH_OUT / 2;  // bf16 [N,64]

    const int B = 256;

    // 1) histogram with ordinal capture (only atomic pass)
    k_zero_i<<<(N + B - 1) / B, B, 0, stream>>>(cnt, N);
    k_hist<<<(E + B - 1) / B, B, 0, stream>>>(ei, cnt, eord, E);

    // 2) rowptr = exclusive scan(cnt); atomic-free fill; degree from CSR
    k_scan_pre<<<NB, 256, 0, stream>>>(cnt, rowptr, bsum, N);
    k_scan_mid<<<1, 256, 0, stream>>>(bsum, NB);
    k_scan_add<<<(N + B - 1) / B, B, 0, stream>>>(rowptr, bsum, N);
    k_fill<<<(E + B - 1) / B, B, 0, stream>>>(ei, w, eord, rowptr, epack, E);
    k_degdinv<<<(N + B - 1) / B, B, 0, stream>>>(rowptr, epack, dinv, N);

    // 3) h1 = x @ W1  (fp32 in, bf16 out)
    k_gemm<CH_HID, false, float><<<(N + 63) / 64, 256, 0, stream>>>(x, W1, h1, N);

    // 4) out1 = b1 + self + neighbor aggregate (bf16 gather, fp32 accum, bf16 out)
    k_agg128<<<(N * 64 + B - 1) / B, B, 0, stream>>>(rowptr, epack, dinv, h1, b1, out1, N);

    // 5) h2 = relu(out1) @ W2  (bf16 in w/ fused relu, bf16 out)
    k_gemm<CH_OUT, true, unsigned short><<<(N + 63) / 64, 256, 0, stream>>>(out1, W2, h2, N);

    // 6) out = log_softmax(b2 + self + aggregate), fused, fp32 into d_out
    k_agg64<<<(N * 64 + B - 1) / B, B, 0, stream>>>(rowptr, epack, dinv, h2, b2, out, N);
}

// Round 7
// 182.729 us; speedup vs baseline: 11.8685x; 1.0853x over previous
//
#include <hip/hip_runtime.h>
#include <math.h>

static constexpr int CH_IN  = 128;
static constexpr int CH_HID = 128;
static constexpr int CH_OUT = 64;
static constexpr int NSH    = 8;     // histogram shards (~XCD count)

typedef __attribute__((ext_vector_type(8))) short bf16x8;
typedef __attribute__((ext_vector_type(4))) float f32x4;

// ---------- bf16 helpers (RNE pack, cheap unpack) ----------

__device__ __forceinline__ float bf2f(unsigned short u) {
    return __uint_as_float(((unsigned int)u) << 16);
}
__device__ __forceinline__ unsigned short f2bf(float f) {
    unsigned int u = __float_as_uint(f);
    u = (u + 0x7fffu + ((u >> 16) & 1u)) >> 16;   // round-to-nearest-even
    return (unsigned short)u;
}
__device__ __forceinline__ unsigned int pack2(float lo, float hi) {
    return (unsigned int)f2bf(lo) | ((unsigned int)f2bf(hi) << 16);
}
__device__ __forceinline__ void unpack2(unsigned int u, float& lo, float& hi) {
    lo = __uint_as_float(u << 16);
    hi = __uint_as_float(u & 0xffff0000u);
}
__device__ __forceinline__ unsigned int relu2(unsigned int u) {
    // zero each bf16 half whose sign bit is set
    unsigned int m = 0;
    if (!(u & 0x8000u)) m |= 0xffffu;
    if (!(u & 0x80000000u)) m |= 0xffff0000u;
    return u & m;
}

// ---------- CSR build: sharded histogram (single returning-atomic pass) ----------

__global__ void k_zero_i(int* __restrict__ p, int n) {
    int i = blockIdx.x * blockDim.x + threadIdx.x;
    if (i < n) p[i] = 0;
}

// shard = blockIdx&7 (~XCD-local under round-robin dispatch); ordinal within (shard,dst)
__global__ void k_hist8(const int* __restrict__ ei, int* __restrict__ cnt_s,
                        int* __restrict__ eord, int E, int N) {
    int e = blockIdx.x * blockDim.x + threadIdx.x;
    if (e < E) {
        int sh = (e >> 8) & (NSH - 1);
        eord[e] = atomicAdd(&cnt_s[sh * N + ei[E + e]], 1);
    }
}

// per-node: exclusive prefix over shards (in place) + total -> cnt[d]
__global__ void k_shardscan(int* __restrict__ cnt_s, int* __restrict__ cnt, int N) {
    int d = blockIdx.x * blockDim.x + threadIdx.x;
    if (d >= N) return;
    int run = 0;
    #pragma unroll
    for (int s = 0; s < NSH; ++s) {
        int idx = s * N + d;
        int c = cnt_s[idx];
        cnt_s[idx] = run;
        run += c;
    }
    cnt[d] = run;
}

// ---------- 3-phase exclusive scan: rowptr[i+1] = sum(cnt[0..i]) ----------

__device__ __forceinline__ int block_incl_scan_256(int v, int lane, int wid) {
    __shared__ int wtot[4];
    int s = v;
    #pragma unroll
    for (int off = 1; off < 64; off <<= 1) {
        int t = __shfl_up(s, off, 64);
        if (lane >= off) s += t;
    }
    if (lane == 63) wtot[wid] = s;
    __syncthreads();
    int woff = 0;
    for (int j = 0; j < wid; ++j) woff += wtot[j];
    return s + woff;
}

__global__ void k_scan_pre(const int* __restrict__ cnt, int* __restrict__ rowptr,
                           int* __restrict__ bsum, int N) {
    const int tid = threadIdx.x, lane = tid & 63, wid = tid >> 6;
    const int i = blockIdx.x * 256 + tid;
    int v = (i < N) ? cnt[i] : 0;
    int s = block_incl_scan_256(v, lane, wid);
    if (i < N) rowptr[i + 1] = s;
    if (tid == 255) bsum[blockIdx.x] = s;
}

__global__ void k_scan_mid(int* __restrict__ bsum, int nb) {
    const int tid = threadIdx.x, lane = tid & 63, wid = tid >> 6;
    int v = (tid < nb) ? bsum[tid] : 0;
    int s = block_incl_scan_256(v, lane, wid);
    if (tid < nb) bsum[tid] = s - v;   // exclusive
}

__global__ void k_scan_add(int* __restrict__ rowptr, const int* __restrict__ bsum, int N) {
    int i = blockIdx.x * blockDim.x + threadIdx.x;
    if (i < N) {
        rowptr[i + 1] += bsum[i >> 8];
        if (i == 0) rowptr[0] = 0;
    }
}

// atomic-free fill: pos = rowptr[d] + shard-prefix + ordinal
__global__ void k_fill(const int* __restrict__ ei, const float* __restrict__ w,
                       const int* __restrict__ eord, const int* __restrict__ rowptr,
                       const int* __restrict__ cnt_s, int2* __restrict__ epack, int E, int N) {
    int e = blockIdx.x * blockDim.x + threadIdx.x;
    if (e < E) {
        int d = ei[E + e];
        int sh = (e >> 8) & (NSH - 1);
        int pos = rowptr[d] + cnt_s[sh * N + d] + eord[e];
        epack[pos] = make_int2(ei[e], __float_as_int(w[e]));
    }
}

// dinv[n] = rsqrt(1 + sum of row weights)  (self-loop weight 1 included)
__global__ void k_degdinv(const int* __restrict__ rowptr, const int2* __restrict__ epack,
                          float* __restrict__ dinv, int N) {
    int n = blockIdx.x * blockDim.x + threadIdx.x;
    if (n >= N) return;
    int beg = rowptr[n], end = rowptr[n + 1];
    float s = 1.0f;
    for (int i = beg; i < end; ++i) s += __int_as_float(epack[i].y);
    dinv[n] = rsqrtf(s);
}

// ---------- weight transpose+convert: Wt[c][k] = bf16(W[k][c]) ----------

__global__ void k_wt(const float* __restrict__ W, unsigned short* __restrict__ Wt,
                     int cols, int total) {
    int i = blockIdx.x * blockDim.x + threadIdx.x;
    if (i < total) {
        int c = i >> 7, k = i & 127;
        Wt[(size_t)c * 128 + k] = f2bf(W[(size_t)k * cols + c]);
    }
}

// ---------- MFMA GEMM: 64 rows/block (4 waves x 16), K=128, bf16 in/out ----------
// A staged bf16 in LDS [64][136] (pad 8 -> ds_read_b128 at the 8-cyc floor).
// B read as bf16x8 from Wt[col][k] (L1/L2-hot).
// v_mfma_f32_16x16x32_bf16: A: row=lane&15, k=(lane>>4)*8+reg
//                           B: col=lane&15, k=(lane>>4)*8+reg
//                           D: col=lane&15, row=(lane>>4)*4+reg  [m89-verified]

template<int COLS, bool RELU_IN, typename TIN>
__global__ void k_gemm_mfma(const TIN* __restrict__ X, const unsigned short* __restrict__ Wt,
                            unsigned short* __restrict__ H, int N) {
    constexpr int NCT = COLS / 16;         // col-tiles: 8 (COLS=128) or 4 (COLS=64)
    __shared__ unsigned short As[64 * 136];
    const int tid = threadIdx.x;
    const int lane = tid & 63, wv = tid >> 6;
    const int row0 = blockIdx.x * 64;

    if constexpr (sizeof(TIN) == 4) {      // fp32 input -> bf16 LDS
        #pragma unroll
        for (int j = 0; j < 8; ++j) {
            int f = j * 256 + tid;         // float4 id (2048 total)
            int row = f >> 5, col = (f & 31) * 4;
            float4 v = make_float4(0.f, 0.f, 0.f, 0.f);
            if (row0 + row < N)
                v = *reinterpret_cast<const float4*>((const float*)X + (size_t)(row0 + row) * CH_IN + col);
            uint2 p;
            p.x = pack2(v.x, v.y);
            p.y = pack2(v.z, v.w);
            *reinterpret_cast<uint2*>(&As[row * 136 + col]) = p;
        }
    } else {                               // bf16 input (optional fused ReLU)
        #pragma unroll
        for (int j = 0; j < 4; ++j) {
            int f = j * 256 + tid;         // uint4 id (1024 total)
            int row = f >> 4, col = (f & 15) * 8;
            uint4 v = make_uint4(0u, 0u, 0u, 0u);
            if (row0 + row < N) {
                v = *reinterpret_cast<const uint4*>((const unsigned short*)X + (size_t)(row0 + row) * CH_IN + col);
                if (RELU_IN) {
                    v.x = relu2(v.x); v.y = relu2(v.y);
                    v.z = relu2(v.z); v.w = relu2(v.w);
                }
            }
            *reinterpret_cast<uint4*>(&As[row * 136 + col]) = v;
        }
    }
    __syncthreads();

    const int rw0  = wv * 16;              // wave's row block
    const int arow = rw0 + (lane & 15);
    const int kgrp = (lane >> 4) * 8;
    f32x4 acc[NCT];
    #pragma unroll
    for (int c = 0; c < NCT; ++c) acc[c] = f32x4{0.f, 0.f, 0.f, 0.f};

    #pragma unroll
    for (int kk = 0; kk < 4; ++kk) {
        bf16x8 af = *reinterpret_cast<const bf16x8*>(&As[arow * 136 + kk * 32 + kgrp]);
        #pragma unroll
        for (int ct = 0; ct < NCT; ++ct) {
            bf16x8 bf = *reinterpret_cast<const bf16x8*>(
                Wt + (size_t)(ct * 16 + (lane & 15)) * 128 + kk * 32 + kgrp);
            acc[ct] = __builtin_amdgcn_mfma_f32_16x16x32_bf16(af, bf, acc[ct], 0, 0, 0);
        }
    }

    const int orow0 = row0 + rw0 + (lane >> 4) * 4;
    const int ocol  = lane & 15;
    #pragma unroll
    for (int ct = 0; ct < NCT; ++ct) {
        #pragma unroll
        for (int r = 0; r < 4; ++r) {
            int row = orow0 + r;
            if (row < N) H[(size_t)row * COLS + ct * 16 + ocol] = f2bf(acc[ct][r]);
        }
    }
}

// ---------- CSR aggregation: wave per node, cooperative metadata, bf16 gathers ----------
// out[n][:] = b + h[n]*dinv[n]^2 + dinv[n] * sum_e h[src_e] * (w_e * dinv[src_e])

__global__ void k_agg128(const int* __restrict__ rowptr, const int2* __restrict__ epack,
                         const float* __restrict__ dinv, const unsigned short* __restrict__ h,
                         const float* __restrict__ b, unsigned short* __restrict__ out, int N) {
    const int node = (blockIdx.x * blockDim.x + threadIdx.x) >> 6;
    const int lane = threadIdx.x & 63;
    if (node >= N) return;
    const int beg = rowptr[node], end = rowptr[node + 1];
    const float dd = dinv[node];
    const unsigned int* hp = (const unsigned int*)h;   // 64 uints per row

    float2 a[8];
    #pragma unroll
    for (int k = 0; k < 8; ++k) a[k] = make_float2(0.f, 0.f);

    for (int i0 = beg; i0 < end; i0 += 64) {
        const int m = min(64, end - i0);
        int s_l = 0; float nm_l = 0.f;
        if (lane < m) {
            int2 p = epack[i0 + lane];
            s_l = p.x;
            nm_l = __int_as_float(p.y) * dinv[p.x];
        }
        int j = 0;
        for (; j + 8 <= m; j += 8) {
            #pragma unroll
            for (int k = 0; k < 8; ++k) {
                int   s  = __shfl(s_l, j + k, 64);
                float nm = __shfl(nm_l, j + k, 64);
                float lo, hi; unpack2(hp[(size_t)s * 64 + lane], lo, hi);
                a[k].x = fmaf(lo, nm, a[k].x);
                a[k].y = fmaf(hi, nm, a[k].y);
            }
        }
        for (; j + 4 <= m; j += 4) {
            #pragma unroll
            for (int k = 0; k < 4; ++k) {
                int   s  = __shfl(s_l, j + k, 64);
                float nm = __shfl(nm_l, j + k, 64);
                float lo, hi; unpack2(hp[(size_t)s * 64 + lane], lo, hi);
                a[k].x = fmaf(lo, nm, a[k].x);
                a[k].y = fmaf(hi, nm, a[k].y);
            }
        }
        for (; j < m; ++j) {
            int   s  = __shfl(s_l, j, 64);
            float nm = __shfl(nm_l, j, 64);
            float lo, hi; unpack2(hp[(size_t)s * 64 + lane], lo, hi);
            a[0].x = fmaf(lo, nm, a[0].x);
            a[0].y = fmaf(hi, nm, a[0].y);
        }
    }
    float sx = ((a[0].x + a[1].x) + (a[2].x + a[3].x)) + ((a[4].x + a[5].x) + (a[6].x + a[7].x));
    float sy = ((a[0].y + a[1].y) + (a[2].y + a[3].y)) + ((a[4].y + a[5].y) + (a[6].y + a[7].y));
    float hnl, hnh; unpack2(hp[(size_t)node * 64 + lane], hnl, hnh);
    float2 bv = ((const float2*)b)[lane];
    sx = fmaf(sx, dd, fmaf(hnl, dd * dd, bv.x));
    sy = fmaf(sy, dd, fmaf(hnh, dd * dd, bv.y));
    ((unsigned int*)out)[(size_t)node * 64 + lane] = pack2(sx, sy);
}

__global__ void k_agg64(const int* __restrict__ rowptr, const int2* __restrict__ epack,
                        const float* __restrict__ dinv, const unsigned short* __restrict__ h,
                        const float* __restrict__ b, float* __restrict__ out, int N) {
    const int node = (blockIdx.x * blockDim.x + threadIdx.x) >> 6;
    const int lane = threadIdx.x & 63;
    if (node >= N) return;
    const int beg = rowptr[node], end = rowptr[node + 1];
    const float dd = dinv[node];

    float a[8];
    #pragma unroll
    for (int k = 0; k < 8; ++k) a[k] = 0.f;

    for (int i0 = beg; i0 < end; i0 += 64) {
        const int m = min(64, end - i0);
        int s_l = 0; float nm_l = 0.f;
        if (lane < m) {
            int2 p = epack[i0 + lane];
            s_l = p.x;
            nm_l = __int_as_float(p.y) * dinv[p.x];
        }
        int j = 0;
        for (; j + 8 <= m; j += 8) {
            #pragma unroll
            for (int k = 0; k < 8; ++k) {
                int   s  = __shfl(s_l, j + k, 64);
                float nm = __shfl(nm_l, j + k, 64);
                a[k] = fmaf(bf2f(h[(size_t)s * 64 + lane]), nm, a[k]);
            }
        }
        for (; j + 4 <= m; j += 4) {
            #pragma unroll
            for (int k = 0; k < 4; ++k) {
                int   s  = __shfl(s_l, j + k, 64);
                float nm = __shfl(nm_l, j + k, 64);
                a[k] = fmaf(bf2f(h[(size_t)s * 64 + lane]), nm, a[k]);
            }
        }
        for (; j < m; ++j) {
            int   s  = __shfl(s_l, j, 64);
            float nm = __shfl(nm_l, j, 64);
            a[0] = fmaf(bf2f(h[(size_t)s * 64 + lane]), nm, a[0]);
        }
    }
    float v = ((a[0] + a[1]) + (a[2] + a[3])) + ((a[4] + a[5]) + (a[6] + a[7]));
    v = fmaf(v, dd, fmaf(bf2f(h[(size_t)node * 64 + lane]), dd * dd, b[lane]));

    float mx = v;
    #pragma unroll
    for (int off = 32; off > 0; off >>= 1) mx = fmaxf(mx, __shfl_xor(mx, off, 64));
    float ex = expf(v - mx);
    float sm = ex;
    #pragma unroll
    for (int off = 32; off > 0; off >>= 1) sm += __shfl_xor(sm, off, 64);
    out[(size_t)node * 64 + lane] = (v - mx) - logf(sm);
}

extern "C" void kernel_launch(void* const* d_in, const int* in_sizes, int n_in,
                              void* d_out, int out_size, void* d_ws, size_t ws_size,
                              hipStream_t stream) {
    const float* x  = (const float*)d_in[0];
    const int*   ei = (const int*)d_in[1];     // [2,E]: src = ei[e], dst = ei[E+e]
    const float* w  = (const float*)d_in[2];
    const float* W1 = (const float*)d_in[3];
    const float* b1 = (const float*)d_in[4];
    const float* W2 = (const float*)d_in[5];
    const float* b2 = (const float*)d_in[6];
    float* out = (float*)d_out;

    const int N = in_sizes[0] / CH_IN;
    const int E = in_sizes[2];
    const int NB = (N + 255) / 256;            // scan blocks (<= 256)

    // workspace carve (float units; epack 8B-aligned, bf16 arrays 16B-aligned)
    float* ws0   = (float*)d_ws;
    float* ws    = ws0;
    float* dinv  = ws;               ws += N;
    int*   rowptr= (int*)ws;         ws += (N + 2);
    int*   cnt   = (int*)ws;         ws += N;
    int*   bsum  = (int*)ws;         ws += 256;
    int*   cnt_s = (int*)ws;         ws += (size_t)NSH * N;
    int*   eord  = (int*)ws;         ws += E;
    int2*  epack = (int2*)ws;        ws += (size_t)2 * E;
    { size_t off = (size_t)(ws - ws0) & 3; if (off) ws += 4 - off; }   // 16B align
    unsigned short* w1t  = (unsigned short*)ws;  ws += (size_t)CH_HID * 128 / 2;
    unsigned short* w2t  = (unsigned short*)ws;  ws += (size_t)CH_OUT * 128 / 2;
    unsigned short* h1   = (unsigned short*)ws;  ws += (size_t)N * CH_HID / 2;
    unsigned short* out1 = (unsigned short*)ws;  ws += (size_t)N * CH_HID / 2;
    unsigned short* h2   = (unsigned short*)ws;  ws += (size_t)N * CH_OUT / 2;

    const int B = 256;

    // 0) weight transpose+convert (tiny)
    k_wt<<<(CH_HID * 128 + B - 1) / B, B, 0, stream>>>(W1, w1t, CH_HID, CH_HID * 128);
    k_wt<<<(CH_OUT * 128 + B - 1) / B, B, 0, stream>>>(W2, w2t, CH_OUT, CH_OUT * 128);

    // 1) sharded histogram with ordinal capture (only atomic pass)
    k_zero_i<<<(NSH * N + B - 1) / B, B, 0, stream>>>(cnt_s, NSH * N);
    k_hist8<<<(E + B - 1) / B, B, 0, stream>>>(ei, cnt_s, eord, E, N);
    k_shardscan<<<(N + B - 1) / B, B, 0, stream>>>(cnt_s, cnt, N);

    // 2) rowptr = exclusive scan(cnt); atomic-free fill; degree from CSR
    k_scan_pre<<<NB, 256, 0, stream>>>(cnt, rowptr, bsum, N);
    k_scan_mid<<<1, 256, 0, stream>>>(bsum, NB);
    k_scan_add<<<(N + B - 1) / B, B, 0, stream>>>(rowptr, bsum, N);
    k_fill<<<(E + B - 1) / B, B, 0, stream>>>(ei, w, eord, rowptr, cnt_s, epack, E, N);
    k_degdinv<<<(N + B - 1) / B, B, 0, stream>>>(rowptr, epack, dinv, N);

    // 3) h1 = x @ W1  (fp32 in -> bf16 LDS -> MFMA -> bf16 out)
    k_gemm_mfma<CH_HID, false, float><<<(N + 63) / 64, 256, 0, stream>>>(x, w1t, h1, N);

    // 4) out1 = b1 + self + neighbor aggregate (bf16 gather, fp32 accum, bf16 out)
    k_agg128<<<(N * 64 + B - 1) / B, B, 0, stream>>>(rowptr, epack, dinv, h1, b1, out1, N);

    // 5) h2 = relu(out1) @ W2  (bf16 in w/ fused relu, MFMA, bf16 out)
    k_gemm_mfma<CH_OUT, true, unsigned short><<<(N + 63) / 64, 256, 0, stream>>>(out1, w2t, h2, N);

    // 6) out = log_softmax(b2 + self + aggregate), fused, fp32 into d_out
    k_agg64<<<(N * 64 + B - 1) / B, B, 0, stream>>>(rowptr, epack, dinv, h2, b2, out, N);
}